// Round 1
// baseline (832.813 us; speedup 1.0000x reference)
//
#include <hip/hip_runtime.h>
#include <cstdint>
#include <cstddef>

typedef short short8 __attribute__((ext_vector_type(8)));
typedef float floatx4 __attribute__((ext_vector_type(4)));
typedef unsigned short ushort4v __attribute__((ext_vector_type(4)));

#define AS1C(p) ((const __attribute__((address_space(1))) void*)(p))
#define AS3(p)  ((__attribute__((address_space(3))) void*)(p))

// round-to-nearest-even float -> bf16 bits
__device__ __forceinline__ unsigned short f2bf(float f) {
    union { float f; unsigned int u; } v; v.f = f;
    unsigned int u = v.u;
    unsigned int r = (u + 0x7fffu + ((u >> 16) & 1u)) >> 16;
    return (unsigned short)r;
}

__device__ __forceinline__ float wave_sum(float s) {
#pragma unroll
    for (int off = 32; off > 0; off >>= 1)
        s += __shfl_xor(s, off, 64);
    return s;
}

// ---------------------------------------------------------------------------
// Kernel 1: per-row l2norm of feats; write f as bf16; atomic scatter into
// per-class sums + counts. One wave (64 lanes) per row of D=512.
// ---------------------------------------------------------------------------
__global__ __launch_bounds__(256) void k_norm_scatter(
    const float* __restrict__ feats, const int* __restrict__ labels,
    unsigned short* __restrict__ fb, float* __restrict__ sums,
    float* __restrict__ counts, int N)
{
    const int gw   = (int)((blockIdx.x * 256u + threadIdx.x) >> 6);
    const int lane = threadIdx.x & 63;
    if (gw >= N) return;

    const float* row = feats + (size_t)gw * 512;
    floatx4 x0 = *(const floatx4*)(row + lane * 4);
    floatx4 x1 = *(const floatx4*)(row + 256 + lane * 4);

    float s = x0.x * x0.x + x0.y * x0.y + x0.z * x0.z + x0.w * x0.w
            + x1.x * x1.x + x1.y * x1.y + x1.z * x1.z + x1.w * x1.w;
    s = wave_sum(s);
    const float inv = 1.0f / fmaxf(sqrtf(s), 1e-12f);

    floatx4 y0 = x0 * inv, y1 = x1 * inv;

    ushort4v b0, b1;
    b0.x = f2bf(y0.x); b0.y = f2bf(y0.y); b0.z = f2bf(y0.z); b0.w = f2bf(y0.w);
    b1.x = f2bf(y1.x); b1.y = f2bf(y1.y); b1.z = f2bf(y1.z); b1.w = f2bf(y1.w);
    *(ushort4v*)(fb + (size_t)gw * 512 + lane * 4)       = b0;
    *(ushort4v*)(fb + (size_t)gw * 512 + 256 + lane * 4) = b1;

    const int lab = labels[gw];
    float* srow = sums + (size_t)lab * 512;
    atomicAdd(srow + lane * 4 + 0, y0.x);
    atomicAdd(srow + lane * 4 + 1, y0.y);
    atomicAdd(srow + lane * 4 + 2, y0.z);
    atomicAdd(srow + lane * 4 + 3, y0.w);
    atomicAdd(srow + 256 + lane * 4 + 0, y1.x);
    atomicAdd(srow + 256 + lane * 4 + 1, y1.y);
    atomicAdd(srow + 256 + lane * 4 + 2, y1.z);
    atomicAdd(srow + 256 + lane * 4 + 3, y1.w);
    if (lane == 0) atomicAdd(counts + lab, 1.0f);
}

// ---------------------------------------------------------------------------
// Kernel 2: new_protos = where(cnt>0, l2norm(0.9*p + 0.1*sum/max(cnt,1)), p)
// One wave per class row; output bf16.
// ---------------------------------------------------------------------------
__global__ __launch_bounds__(256) void k_update(
    const float* __restrict__ protos, const float* __restrict__ sums,
    const float* __restrict__ counts, unsigned short* __restrict__ pb, int C)
{
    const int c    = (int)((blockIdx.x * 256u + threadIdx.x) >> 6);
    const int lane = threadIdx.x & 63;
    if (c >= C) return;

    const float cnt = counts[c];
    const float* prow = protos + (size_t)c * 512;
    const float* srow = sums   + (size_t)c * 512;
    floatx4 p0 = *(const floatx4*)(prow + lane * 4);
    floatx4 p1 = *(const floatx4*)(prow + 256 + lane * 4);
    floatx4 s0 = *(const floatx4*)(srow + lane * 4);
    floatx4 s1 = *(const floatx4*)(srow + 256 + lane * 4);

    const float rc = 0.1f / fmaxf(cnt, 1.0f);
    floatx4 v0 = p0 * 0.9f + s0 * rc;
    floatx4 v1 = p1 * 0.9f + s1 * rc;

    float nn = v0.x * v0.x + v0.y * v0.y + v0.z * v0.z + v0.w * v0.w
             + v1.x * v1.x + v1.y * v1.y + v1.z * v1.z + v1.w * v1.w;
    nn = wave_sum(nn);
    const float inv = 1.0f / fmaxf(sqrtf(nn), 1e-12f);

    floatx4 o0, o1;
    if (cnt > 0.0f) { o0 = v0 * inv; o1 = v1 * inv; }
    else            { o0 = p0;       o1 = p1;       }

    ushort4v b0, b1;
    b0.x = f2bf(o0.x); b0.y = f2bf(o0.y); b0.z = f2bf(o0.z); b0.w = f2bf(o0.w);
    b1.x = f2bf(o1.x); b1.y = f2bf(o1.y); b1.z = f2bf(o1.z); b1.w = f2bf(o1.w);
    *(ushort4v*)(pb + (size_t)c * 512 + lane * 4)       = b0;
    *(ushort4v*)(pb + (size_t)c * 512 + 256 + lane * 4) = b1;
}

// ---------------------------------------------------------------------------
// Kernel 3: sim[N,C] = f[N,K] @ P[C,K]^T, bf16 inputs, fp32 out.
// m97-style: 128x128 tile, BK=64, 16x16x32 bf16 MFMA, global_load_lds x16.
// Block = 256 threads = 4 waves in 2x2; each wave does 64x64 (4x4 MFMA tiles).
// ---------------------------------------------------------------------------
__global__ __launch_bounds__(256, 2) void k_gemm(
    const unsigned short* __restrict__ A, const unsigned short* __restrict__ B,
    float* __restrict__ out, int N, int C, int K)
{
    __shared__ unsigned short As[128 * 64];  // 16 KB, row-major [128][64]
    __shared__ unsigned short Bs[128 * 64];  // 16 KB

    const int tid   = threadIdx.x;
    const int lane  = tid & 63;
    const int wv    = tid >> 6;
    const int waveM = wv >> 1, waveN = wv & 1;
    const int quad  = lane >> 4, l16 = lane & 15;
    const size_t m0 = (size_t)blockIdx.y * 128;
    const size_t n0 = (size_t)blockIdx.x * 128;

    floatx4 zero = {0.0f, 0.0f, 0.0f, 0.0f};
    floatx4 acc[4][4];
#pragma unroll
    for (int i = 0; i < 4; ++i)
#pragma unroll
        for (int j = 0; j < 4; ++j) acc[i][j] = zero;

    const int arow = tid >> 3;        // 0..31  (row within a 32-row staging slab)
    const int kc8  = (tid & 7) * 8;   // k-chunk offset in elements

    for (int k0 = 0; k0 < K; k0 += 64) {
        // stage A tile: 128x64 bf16; 4 slabs of 32 rows; 16B per lane,
        // LDS dest = wave-uniform base + lane*16 (layout constraint honored)
#pragma unroll
        for (int t = 0; t < 4; ++t) {
            const unsigned short* ga = A + (m0 + (size_t)(t * 32 + arow)) * K + (k0 + kc8);
            __builtin_amdgcn_global_load_lds(AS1C(ga), AS3(As + (t * 256 + tid) * 8), 16, 0, 0);
        }
#pragma unroll
        for (int t = 0; t < 4; ++t) {
            const unsigned short* gb = B + (n0 + (size_t)(t * 32 + arow)) * K + (k0 + kc8);
            __builtin_amdgcn_global_load_lds(AS1C(gb), AS3(Bs + (t * 256 + tid) * 8), 16, 0, 0);
        }
        __builtin_amdgcn_s_waitcnt(0);   // drain vmcnt before barrier
        __syncthreads();

#pragma unroll
        for (int s = 0; s < 2; ++s) {    // two K=32 MFMA steps per BK=64
            short8 af[4], bfr[4];
#pragma unroll
            for (int m = 0; m < 4; ++m)
                af[m] = *(const short8*)(As + (waveM * 64 + m * 16 + l16) * 64 + s * 32 + quad * 8);
#pragma unroll
            for (int n = 0; n < 4; ++n)
                bfr[n] = *(const short8*)(Bs + (waveN * 64 + n * 16 + l16) * 64 + s * 32 + quad * 8);
#pragma unroll
            for (int m = 0; m < 4; ++m)
#pragma unroll
                for (int n = 0; n < 4; ++n)
                    acc[m][n] = __builtin_amdgcn_mfma_f32_16x16x32_bf16(af[m], bfr[n], acc[m][n], 0, 0, 0);
        }
        __syncthreads();
    }

    // epilogue: C/D layout col=lane&15, row=(lane>>4)*4+reg
#pragma unroll
    for (int m = 0; m < 4; ++m) {
        const size_t r0 = m0 + (size_t)(waveM * 64 + m * 16 + quad * 4);
#pragma unroll
        for (int n = 0; n < 4; ++n) {
            const size_t c = n0 + (size_t)(waveN * 64 + n * 16 + l16);
#pragma unroll
            for (int r = 0; r < 4; ++r)
                out[(r0 + r) * (size_t)C + c] = acc[m][n][r];
        }
    }
}

// ---------------------------------------------------------------------------
extern "C" void kernel_launch(void* const* d_in, const int* in_sizes, int n_in,
                              void* d_out, int out_size, void* d_ws, size_t ws_size,
                              hipStream_t stream)
{
    const float* feats  = (const float*)d_in[0];
    const float* protos = (const float*)d_in[1];
    const int*   labels = (const int*)d_in[2];
    float* sim = (float*)d_out;

    const int D = 512;
    const int N = in_sizes[0] / D;   // 65536
    const int C = in_sizes[1] / D;   // 1024

    char* w = (char*)d_ws;
    unsigned short* fb = (unsigned short*)w;                       // N*D bf16 = 64 MB
    size_t off = (size_t)N * D * 2;
    float* sums = (float*)(w + off);                               // C*D f32 = 2 MB
    size_t sums_bytes = (size_t)C * D * 4;
    float* counts = (float*)(w + off + sums_bytes);                // C f32 = 4 KB
    unsigned short* pb = (unsigned short*)(w + off + sums_bytes + (size_t)C * 4); // C*D bf16

    // zero the atomic accumulators (ws is poisoned 0xAA before every launch)
    hipMemsetAsync(sums, 0, sums_bytes + (size_t)C * 4, stream);

    k_norm_scatter<<<dim3(N / 4), dim3(256), 0, stream>>>(feats, labels, fb, sums, counts, N);
    k_update<<<dim3(C / 4), dim3(256), 0, stream>>>(protos, sums, counts, pb, C);

    dim3 g(C / 128, N / 128);   // (8, 512)
    k_gemm<<<g, dim3(256), 0, stream>>>(fb, pb, sim, N, C, D);
}